// Round 17
// baseline (189.911 us; speedup 1.0000x reference)
//
#include <hip/hip_runtime.h>
#include <math.h>

// Shapes (fixed)
#define B_ 4
#define S_ 256
#define N_ 32
#define H_ 256
#define NH_ 8
#define HD_ 32
#define FF_ 512
#define BN_ 128
#define M_ 32768   // BN_*S_
#define BS_ 1024   // B_*S_

typedef __attribute__((ext_vector_type(8))) short short8;
typedef __attribute__((ext_vector_type(4))) short short4v;
typedef __attribute__((ext_vector_type(4))) float f32x4;
typedef __attribute__((ext_vector_type(16))) float f32x16;
typedef __attribute__((ext_vector_type(4))) int i32x4;

__device__ __forceinline__ unsigned short f2bf(float f) {
  unsigned u = __builtin_bit_cast(unsigned, f);
  u = (u + 0x7FFFu + ((u >> 16) & 1u)) >> 16;
  return (unsigned short)u;
}
__device__ __forceinline__ float bf2f(unsigned short h) {
  unsigned u = ((unsigned)h) << 16;
  return __builtin_bit_cast(float, u);
}

// Direct global->LDS DMA, 16B per lane (lands at wave-uniform base + lane*16).
__device__ __forceinline__ void gload16(const void* g, void* l) {
  __builtin_amdgcn_global_load_lds(
      (const __attribute__((address_space(1))) unsigned*)g,
      (__attribute__((address_space(3))) unsigned*)l, 16, 0, 0);
}

// ---------------------------------------------------------------------------
// cvtts + prep merged (one launch):
// blocks 0..2559:    W[K][N] fp32 -> Wt[N][K] bf16 (8 weight regions)
// blocks 2560..3583: ts[bs][h]
// blocks 3584..7679: prep rows: flatb = bf16(seq), fpb = bf16(seq + ts_inline)
// ---------------------------------------------------------------------------
__global__ __launch_bounds__(256)
void cvtts_kernel(const float* __restrict__ q_w, const float* __restrict__ k_w,
                  const float* __restrict__ v_w, const float* __restrict__ o_w,
                  const float* __restrict__ tq_w, const float* __restrict__ tk_w,
                  const float* __restrict__ ff1_w, const float* __restrict__ ff2_w,
                  unsigned short* __restrict__ wqk, unsigned short* __restrict__ wv,
                  unsigned short* __restrict__ wo, unsigned short* __restrict__ wtqtk,
                  unsigned short* __restrict__ wff1, unsigned short* __restrict__ wff2,
                  const float* __restrict__ reg, const float* __restrict__ tr,
                  const int* __restrict__ codes, const float* __restrict__ semb,
                  const float* __restrict__ reg_w, const float* __restrict__ reg_b,
                  const float* __restrict__ tr_w, const float* __restrict__ tr_b,
                  float* __restrict__ ts,
                  const float* __restrict__ seq,
                  unsigned short* __restrict__ flatb,
                  unsigned short* __restrict__ fpb) {
  const int bid = blockIdx.x, tid = threadIdx.x;
  if (bid >= 3584) {   // prep region
    const int row = (bid - 3584) * 8 + (tid >> 5);
    const int c0 = (tid & 31) * 8;
    const int bn = row >> 8, s = row & 255;
    const int b = bn >> 5, n = bn & 31;
    const int bs = (b << 8) + s;
    int c = codes[bs];
    c = c < 0 ? 0 : (c > 7 ? 7 : c);
    const float r = reg[bs], t = tr[bs];
    const float* sp = &seq[(((bs << 5)) + n) * 256 + c0];
    const float4 a0 = *(const float4*)sp, a1 = *(const float4*)(sp + 4);
    short8 fv, gv;
    float av[8] = {a0.x, a0.y, a0.z, a0.w, a1.x, a1.y, a1.z, a1.w};
#pragma unroll
    for (int j = 0; j < 8; ++j) {
      const int hcol = c0 + j;
      const float tsv = semb[c * H_ + hcol] + r * reg_w[hcol] + reg_b[hcol]
                        + t * tr_w[hcol] + tr_b[hcol];
      fv[j] = (short)f2bf(av[j]);
      gv[j] = (short)f2bf(av[j] + tsv);
    }
    *(short8*)&flatb[row * 256 + c0] = fv;
    *(short8*)&fpb[row * 256 + c0] = gv;
    return;
  }
  if (bid >= 2560) {   // time_state region
    const int bs = bid - 2560;
    int c = codes[bs];
    c = c < 0 ? 0 : (c > 7 ? 7 : c);
    const float r = reg[bs], t = tr[bs];
    ts[bs * H_ + tid] = semb[c * H_ + tid] + r * reg_w[tid] + reg_b[tid]
                        + t * tr_w[tid] + tr_b[tid];
    return;
  }
  const float* src; unsigned short* dst; int ns, K, base;
  if (bid < 256)       { src = q_w;   dst = wqk;           ns = 8; K = 256; base = 0; }
  else if (bid < 512)  { src = k_w;   dst = wqk + 65536;   ns = 8; K = 256; base = 256; }
  else if (bid < 768)  { src = v_w;   dst = wv;            ns = 8; K = 256; base = 512; }
  else if (bid < 1024) { src = o_w;   dst = wo;            ns = 8; K = 256; base = 768; }
  else if (bid < 1280) { src = tq_w;  dst = wtqtk;         ns = 8; K = 256; base = 1024; }
  else if (bid < 1536) { src = tk_w;  dst = wtqtk + 65536; ns = 8; K = 256; base = 1280; }
  else if (bid < 2048) { src = ff1_w; dst = wff1;          ns = 9; K = 256; base = 1536; }
  else                 { src = ff2_w; dst = wff2;          ns = 8; K = 512; base = 2048; }
  const int idx = (bid - base) * 256 + tid;
  const int k = idx >> ns, n = idx & ((1 << ns) - 1);
  dst[n * K + k] = f2bf(src[idx]);
}

// ---------------------------------------------------------------------------
// Combined projection kernel, 128x256 tiles (acc[4][8] per wave) to double
// the MFMA:staging ratio (K=256 is short; the 2-barrier loop was
// staging-bound at 128x128 -- MfmaUtil 11%).
//  region 0 (blocks 0..511):   qk  (fpb @ wqk): m0=(idx&255)*128, n0=(idx>>8)*256
//  region 1 (blocks 512..767): v   (flatb @ wv): m0=idx*128, n0=0
//  region 2 (blocks 768..783): tqtk (ts @ wtqtk): m0=(idx&7)*128, n0=(idx>>3)*256
// T2 swizzle: pre-swizzled global source granule + XOR'd reads.
// ---------------------------------------------------------------------------
__global__ __launch_bounds__(256)
void proj_kernel(const unsigned short* __restrict__ fpb,
                 const unsigned short* __restrict__ flatb,
                 const float* __restrict__ ts,
                 const unsigned short* __restrict__ wqk,
                 const unsigned short* __restrict__ wv,
                 const unsigned short* __restrict__ wtqtk,
                 const float* __restrict__ q_b, const float* __restrict__ k_b,
                 const float* __restrict__ v_b,
                 const float* __restrict__ tq_b, const float* __restrict__ tk_b,
                 unsigned short* __restrict__ qkb, unsigned short* __restrict__ vb,
                 unsigned short* __restrict__ tqtkb, float c2) {
  __shared__ unsigned short As[128 * 64];   // 16 KB
  __shared__ unsigned short Bs[256 * 64];   // 32 KB
  const int bid = blockIdx.x, tid = threadIdx.x;
  const int l = tid & 63, w = tid >> 6;
  const int wr = w >> 1, wc = w & 1;        // wave = (row half 64, col half 128)
  const int lr = l & 15, lg = l >> 4;
  const int sw = (lr & 7) << 3;             // read-side XOR (shorts)

  int region, m0, n0, NOUT;
  const unsigned short* Ab = nullptr;
  const float* Af = nullptr;
  const unsigned short* Wt;
  const float* b0; const float* b1;
  unsigned short* Cv; float scl;
  if (bid < 512) {
    region = 0; m0 = (bid & 255) * 128; n0 = (bid >> 8) * 256; NOUT = 512;
    Ab = fpb; Wt = wqk; b0 = q_b; b1 = k_b; Cv = qkb; scl = c2;
  } else if (bid < 768) {
    const int idx = bid - 512;
    region = 1; m0 = idx * 128; n0 = 0; NOUT = 256;
    Ab = flatb; Wt = wv; b0 = v_b; b1 = v_b; Cv = vb; scl = 1.0f;
  } else {
    const int idx = bid - 768;
    region = 2; m0 = (idx & 7) * 128; n0 = (idx >> 3) * 256; NOUT = 512;
    Af = ts; Wt = wtqtk; b0 = tq_b; b1 = tk_b; Cv = tqtkb; scl = 0.25f * c2;
  }

  f32x4 acc[4][8] = {};
  const int cg = (l & 7) ^ (l >> 3);   // pre-swizzled source granule
  const unsigned short* ga = (region != 2)
      ? Ab + (m0 + w * 32 + (l >> 3)) * 256 + cg * 8 : nullptr;
  const unsigned short* gb = Wt + (n0 + w * 64 + (l >> 3)) * 256 + cg * 8;

  for (int k0 = 0; k0 < 256; k0 += 64) {
    if (region != 2) {
#pragma unroll
      for (int i = 0; i < 4; ++i)
        gload16(ga + k0 + i * 8 * 256, &As[(w * 32 + i * 8) * 64]);
    } else {
#pragma unroll
      for (int i = 0; i < 8; ++i) {
        const int seg = i * 256 + tid;
        const int r = seg >> 4, c4 = (seg & 15) * 4;
        const float4 a4 = *(const float4*)&Af[(m0 + r) * 256 + k0 + c4];
        short4v sv;
        sv[0] = (short)f2bf(a4.x); sv[1] = (short)f2bf(a4.y);
        sv[2] = (short)f2bf(a4.z); sv[3] = (short)f2bf(a4.w);
        *(short4v*)&As[r * 64 + (c4 ^ ((r & 7) << 3))] = sv;
      }
    }
#pragma unroll
    for (int i = 0; i < 8; ++i)
      gload16(gb + k0 + i * 8 * 256, &Bs[(w * 64 + i * 8) * 64]);
    __syncthreads();
#pragma unroll
    for (int ks = 0; ks < 2; ++ks) {
      short8 af[4], bfr[8];
#pragma unroll
      for (int qt = 0; qt < 4; ++qt)
        af[qt] = *(const short8*)&As[(wr * 64 + qt * 16 + lr) * 64
                                     + ((ks * 32 + lg * 8) ^ sw)];
#pragma unroll
      for (int nt = 0; nt < 8; ++nt)
        bfr[nt] = *(const short8*)&Bs[(wc * 128 + nt * 16 + lr) * 64
                                      + ((ks * 32 + lg * 8) ^ sw)];
#pragma unroll
      for (int qt = 0; qt < 4; ++qt)
#pragma unroll
        for (int nt = 0; nt < 8; ++nt)
          acc[qt][nt] = __builtin_amdgcn_mfma_f32_16x16x32_bf16(
              af[qt], bfr[nt], acc[qt][nt], 0, 0, 0);
    }
    __syncthreads();
  }

#pragma unroll
  for (int qt = 0; qt < 4; ++qt) {
#pragma unroll
    for (int nt = 0; nt < 8; ++nt) {
      const int col = n0 + wc * 128 + nt * 16 + lr;
      const float bsv = (col < 256) ? b0[col] : b1[col - 256];
      const float sc = (col < 256) ? scl : 1.0f;
#pragma unroll
      for (int i = 0; i < 4; ++i) {
        const int row = m0 + wr * 64 + qt * 16 + (lg << 2) + i;
        Cv[row * NOUT + col] = f2bf((acc[qt][nt][i] + bsv) * sc);
      }
    }
  }
}

// ---------------------------------------------------------------------------
// bf16 MFMA GEMM (ff1 only): C = gelu(A @ W + bias), bf16 out.
// Same 128x256 tile + T2 swizzle as proj.
// ---------------------------------------------------------------------------
template<int K, int NOUT>
__global__ __launch_bounds__(256)
void mmb_kernel(const unsigned short* __restrict__ Ab,
                const unsigned short* __restrict__ Wt,
                const float* __restrict__ bias,
                unsigned short* __restrict__ Cv) {
  __shared__ unsigned short As[128 * 64];
  __shared__ unsigned short Bs[256 * 64];
  const int tid = threadIdx.x;
  const int m0 = blockIdx.x * 128, n0 = blockIdx.y * 256;
  const int l = tid & 63, w = tid >> 6;
  const int wr = w >> 1, wc = w & 1;
  const int lr = l & 15, lg = l >> 4;
  const int sw = (lr & 7) << 3;
  f32x4 acc[4][8] = {};

  const int cg = (l & 7) ^ (l >> 3);
  const unsigned short* ga = Ab + (m0 + w * 32 + (l >> 3)) * K + cg * 8;
  const unsigned short* gb = Wt + (n0 + w * 64 + (l >> 3)) * K + cg * 8;

  for (int k0 = 0; k0 < K; k0 += 64) {
#pragma unroll
    for (int i = 0; i < 4; ++i)
      gload16(ga + k0 + i * 8 * K, &As[(w * 32 + i * 8) * 64]);
#pragma unroll
    for (int i = 0; i < 8; ++i)
      gload16(gb + k0 + i * 8 * K, &Bs[(w * 64 + i * 8) * 64]);
    __syncthreads();
#pragma unroll
    for (int ks = 0; ks < 2; ++ks) {
      short8 af[4], bfr[8];
#pragma unroll
      for (int qt = 0; qt < 4; ++qt)
        af[qt] = *(const short8*)&As[(wr * 64 + qt * 16 + lr) * 64
                                     + ((ks * 32 + lg * 8) ^ sw)];
#pragma unroll
      for (int nt = 0; nt < 8; ++nt)
        bfr[nt] = *(const short8*)&Bs[(wc * 128 + nt * 16 + lr) * 64
                                      + ((ks * 32 + lg * 8) ^ sw)];
#pragma unroll
      for (int qt = 0; qt < 4; ++qt)
#pragma unroll
        for (int nt = 0; nt < 8; ++nt)
          acc[qt][nt] = __builtin_amdgcn_mfma_f32_16x16x32_bf16(
              af[qt], bfr[nt], acc[qt][nt], 0, 0, 0);
    }
    __syncthreads();
  }

#pragma unroll
  for (int qt = 0; qt < 4; ++qt) {
#pragma unroll
    for (int nt = 0; nt < 8; ++nt) {
      const int col = n0 + wc * 128 + nt * 16 + lr;
      const float bsv = bias[col];
#pragma unroll
      for (int i = 0; i < 4; ++i) {
        const int row = m0 + wr * 64 + qt * 16 + (lg << 2) + i;
        float v = acc[qt][nt][i] + bsv;
        v = 0.5f * v * (1.0f + erff(v * 0.70710678118654752f));
        Cv[row * NOUT + col] = f2bf(v);
      }
    }
  }
}

// ---------------------------------------------------------------------------
// Fused GEMM (NOUT=256, full row per block) + residual + LayerNorm.
// FINAL=false: write bf16 [M][256] (LN1). FINAL=true: fp32 *valid scatter.
// (unchanged)
// ---------------------------------------------------------------------------
template<int K, bool FINAL>
__global__ __launch_bounds__(256, 2)
void gemmln_kernel(const unsigned short* __restrict__ Ab,   // [M][K] bf16
                   const unsigned short* __restrict__ Wt,   // [256][K] bf16
                   const float* __restrict__ bias,
                   const unsigned short* __restrict__ resb, // [M][256] bf16
                   const float* __restrict__ g, const float* __restrict__ bb,
                   const int* __restrict__ valid,
                   void* __restrict__ out) {
  __shared__ unsigned short As[64 * 64];    // 8 KB
  __shared__ unsigned short Bs[256 * 64];   // 32 KB
  __shared__ float Red[4][64][2];           // 2 KB
  const int tid = threadIdx.x;
  const int m0 = blockIdx.x * 64;
  const int l = tid & 63, w = tid >> 6;     // w = col quarter
  const int lr = l & 15, lg = l >> 4;
  f32x4 acc[4][4] = {};

  const unsigned short* ga = Ab + (m0 + w * 16 + (l >> 3)) * K + (l & 7) * 8;
  const unsigned short* gb = Wt + (w * 64 + (l >> 3)) * K + (l & 7) * 8;

  for (int k0 = 0; k0 < K; k0 += 64) {
#pragma unroll
    for (int i = 0; i < 2; ++i)
      gload16(ga + k0 + i * 8 * K, &As[(w * 16 + i * 8) * 64]);
#pragma unroll
    for (int i = 0; i < 8; ++i)
      gload16(gb + k0 + i * 8 * K, &Bs[(w * 64 + i * 8) * 64]);
    __syncthreads();
#pragma unroll
    for (int ks = 0; ks < 2; ++ks) {
      short8 af[4], bfr[4];
#pragma unroll
      for (int qt = 0; qt < 4; ++qt)
        af[qt] = *(const short8*)&As[(qt * 16 + lr) * 64 + ks * 32 + lg * 8];
#pragma unroll
      for (int nt = 0; nt < 4; ++nt)
        bfr[nt] = *(const short8*)&Bs[(w * 64 + nt * 16 + lr) * 64 + ks * 32 + lg * 8];
#pragma unroll
      for (int qt = 0; qt < 4; ++qt)
#pragma unroll
        for (int nt = 0; nt < 4; ++nt)
          acc[qt][nt] = __builtin_amdgcn_mfma_f32_16x16x32_bf16(
              af[qt], bfr[nt], acc[qt][nt], 0, 0, 0);
    }
    __syncthreads();
  }

  // Phase A: x = acc + bias + residual; per-row partial sums -> Red[w]
#pragma unroll
  for (int qt = 0; qt < 4; ++qt) {
#pragma unroll
    for (int i = 0; i < 4; ++i) {
      const int rl = qt * 16 + (lg << 2) + i;
      const int row = m0 + rl;
      float s1 = 0.0f, s2 = 0.0f;
#pragma unroll
      for (int nt = 0; nt < 4; ++nt) {
        const int col = w * 64 + nt * 16 + lr;
        float v = acc[qt][nt][i] + bias[col] + bf2f(resb[row * 256 + col]);
        acc[qt][nt][i] = v;
        s1 += v; s2 += v * v;
      }
      s1 += __shfl_xor(s1, 1); s2 += __shfl_xor(s2, 1);
      s1 += __shfl_xor(s1, 2); s2 += __shfl_xor(s2, 2);
      s1 += __shfl_xor(s1, 4); s2 += __shfl_xor(s2, 4);
      s1 += __shfl_xor(s1, 8); s2 += __shfl_xor(s2, 8);
      if (lr == 0) { Red[w][rl][0] = s1; Red[w][rl][1] = s2; }
    }
  }
  __syncthreads();

  // Phase B: combine 4 quarters, normalize, write own cols
#pragma unroll
  for (int qt = 0; qt < 4; ++qt) {
#pragma unroll
    for (int i = 0; i < 4; ++i) {
      const int rl = qt * 16 + (lg << 2) + i;
      const int row = m0 + rl;
      const float s1 = (Red[0][rl][0] + Red[1][rl][0])
                     + (Red[2][rl][0] + Red[3][rl][0]);
      const float s2 = (Red[0][rl][1] + Red[1][rl][1])
                     + (Red[2][rl][1] + Red[3][rl][1]);
      const float mean = s1 * (1.0f / 256.0f);
      const float var = s2 * (1.0f / 256.0f) - mean * mean;
      const float rstd = rsqrtf(var + 1e-5f);
      if (FINAL) {
        const int bn = row >> 8, s = row & 255;
        const int b = bn >> 5, n = bn & 31;
        const float vm = (valid[((b << 8) + s) * 32 + n] != 0) ? 1.0f : 0.0f;
        float* op = (float*)out + ((((b << 8) + s) << 5) + n) * 256;
#pragma unroll
        for (int nt = 0; nt < 4; ++nt) {
          const int col = w * 64 + nt * 16 + lr;
          op[col] = ((acc[qt][nt][i] - mean) * rstd * g[col] + bb[col]) * vm;
        }
      } else {
        unsigned short* op = (unsigned short*)out + row * 256;
#pragma unroll
        for (int nt = 0; nt < 4; ++nt) {
          const int col = w * 64 + nt * 16 + lr;
          op[col] = f2bf((acc[qt][nt][i] - mean) * rstd * g[col] + bb[col]);
        }
      }
    }
  }
}

// ---------------------------------------------------------------------------
// One key-group step of the swapped-operand flash attention.
// ---------------------------------------------------------------------------
__device__ __forceinline__ void attn_group(
    const int kbase, const int qa, const int hi, const int lq,
    const short8* __restrict__ qf,
    const char* __restrict__ KsB, const char* __restrict__ VsB,
    const unsigned long long bm0, const unsigned long long bm1,
    const unsigned long long bm2, const unsigned long long bm3,
    f32x16& oacc, float& lrun) {
  f32x16 s = {};
#pragma unroll
  for (int df = 0; df < 4; ++df) {
    const int key = kbase + lq;
    const short8 akf = *(const short8*)(
        KsB + key * 128 + ((df * 32 + hi * 16) ^ ((key & 7) << 4)));
    s = __builtin_amdgcn_mfma_f32_32x32x16_bf16(akf, qf[df], s, 0, 0, 0);
  }
  const unsigned long long bmc = (kbase < 64) ? bm0 : (kbase < 128) ? bm1
                               : (kbase < 192) ? bm2 : bm3;
  const unsigned wnd = (kbase & 32) ? (unsigned)(bmc >> 32) : (unsigned)bmc;
  float p[16];
#pragma unroll
  for (int r = 0; r < 16; ++r) {
    const int crow = (r & 3) + 8 * (r >> 2) + 4 * hi;
    const int key = kbase + crow;
    const bool ok = (key <= qa) && (((wnd >> crow) & 1u) != 0u);
    p[r] = ok ? __builtin_amdgcn_exp2f(s[r]) : 0.0f;
  }
  float rs = ((p[0] + p[1]) + (p[2] + p[3])) + ((p[4] + p[5]) + (p[6] + p[7]))
           + ((p[8] + p[9]) + (p[10] + p[11])) + ((p[12] + p[13]) + (p[14] + p[15]));
  rs += __shfl_xor(rs, 32);
  lrun += rs;
  unsigned wds[8];
#pragma unroll
  for (int i2 = 0; i2 < 8; ++i2)
    wds[i2] = (unsigned)f2bf(p[2 * i2]) | ((unsigned)f2bf(p[2 * i2 + 1]) << 16);
  unsigned xw[8];
#pragma unroll
  for (int i2 = 0; i2 < 8; ++i2)
    xw[i2] = (unsigned)__shfl_xor((int)wds[i2], 32);
  i32x4 f0, f1;
  f0[0] = (int)(hi ? xw[2] : wds[0]);
  f0[1] = (int)(hi ? xw[3] : wds[1]);
  f0[2] = (int)(hi ? wds[2] : xw[0]);
  f0[3] = (int)(hi ? wds[3] : xw[1]);
  f1[0] = (int)(hi ? xw[6] : wds[4]);
  f1[1] = (int)(hi ? xw[7] : wds[5]);
  f1[2] = (int)(hi ? wds[6] : xw[4]);
  f1[3] = (int)(hi ? wds[7] : xw[5]);
  const short8 pf0 = __builtin_bit_cast(short8, f0);
  const short8 pf1 = __builtin_bit_cast(short8, f1);
  {
    const short8 avf = *(const short8*)(
        VsB + lq * 512 + (((kbase + hi * 8) * 2) ^ ((lq & 7) << 4)));
    oacc = __builtin_amdgcn_mfma_f32_32x32x16_bf16(avf, pf0, oacc, 0, 0, 0);
  }
  {
    const short8 avf = *(const short8*)(
        VsB + lq * 512 + (((kbase + 16 + hi * 8) * 2) ^ ((lq & 7) << 4)));
    oacc = __builtin_amdgcn_mfma_f32_32x32x16_bf16(avf, pf1, oacc, 0, 0, 0);
  }
}

// ---------------------------------------------------------------------------
// Attention (unchanged): 8 waves, 48KB LDS, balanced helper waves;
// XCD swizzle; async K'-staging; direct stores.
// ---------------------------------------------------------------------------
__global__ __launch_bounds__(512, 4)
void attn6_kernel(const unsigned short* __restrict__ qkb,   // [M][512] q|k
                  const unsigned short* __restrict__ vb,    // [M][256]
                  const unsigned short* __restrict__ tqtkb, // [BS][512] tq|tk
                  const int* __restrict__ valid,
                  unsigned short* __restrict__ ao) {
  __shared__ __align__(16) char KsB[256 * 128];   // K' [key][d64]; merge alias
  __shared__ __align__(16) char VsB[32 * 512];    // V^T [dv][key], swizzled

  const int bn = blockIdx.x & 127;      // XCD swizzle
  const int h = blockIdx.x >> 7;
  const int b = bn >> 5, n = bn & 31;
  const int tid = threadIdx.x, l = tid & 63, w = tid >> 6;  // w = query chunk
  const int lq = l & 31, hi = l >> 5;
  const int qa = w * 32 + lq;          // this lane's query row

  const unsigned long long bm0 = __ballot(valid[((b << 8) + 0   + l) * 32 + n] != 0);
  const unsigned long long bm1 = __ballot(valid[((b << 8) + 64  + l) * 32 + n] != 0);
  const unsigned long long bm2 = __ballot(valid[((b << 8) + 128 + l) * 32 + n] != 0);
  const unsigned long long bm3 = __ballot(valid[((b << 8) + 192 + l) * 32 + n] != 0);

  short8 qf[4];
  {
    const unsigned short* qp = &qkb[((bn << 8) + qa) * 512 + (h << 5)];
    const unsigned short* tp = &tqtkb[((b << 8) + qa) * 512 + (h << 5)];
    qf[0] = *(const short8*)&qp[hi * 8];
    qf[1] = *(const short8*)&qp[16 + hi * 8];
    qf[2] = *(const short8*)&tp[hi * 8];
    qf[3] = *(const short8*)&tp[16 + hi * 8];
  }

  // stage K' via async DMA with pre-swizzled source
  {
    const int cp = (l & 7) ^ (l >> 3);
    const unsigned short* base0 = (cp < 4)
        ? &qkb[((bn << 8) + (l >> 3)) * 512 + 256 + (h << 5) + cp * 8]
        : &tqtkb[((b << 8) + (l >> 3)) * 512 + 256 + (h << 5) + (cp - 4) * 8];
#pragma unroll
    for (int i = 0; i < 4; ++i) {
      const int kb0 = i * 64 + w * 8;   // wave-uniform base key
      gload16(base0 + kb0 * 512, KsB + kb0 * 128);
    }
  }
  // stage V^T (manual transpose), swizzled
#pragma unroll
  for (int i = 0; i < 2; ++i) {
    const int e = i * 512 + tid;
    const int key = e >> 2, c = e & 3;
    const short8 v = *(const short8*)&vb[((bn << 8) + key) * 256 + (h << 5) + c * 8];
#pragma unroll
    for (int j = 0; j < 8; ++j) {
      const int dv = c * 8 + j;
      *(unsigned short*)(VsB + dv * 512 + ((key * 2) ^ ((dv & 7) << 4))) =
          (unsigned short)v[j];
    }
  }
  __syncthreads();

  f32x16 oacc = {}, oacc2 = {};
  float lrun = 0.0f, lrun2 = 0.0f;

  const int gstart = (w >= 4) ? (w - 3) : 0;
  for (int g = gstart; g <= w; ++g)
    attn_group(g << 5, qa, hi, lq, qf, KsB, VsB, bm0, bm1, bm2, bm3, oacc, lrun);

  if (w < 4) {
    const int ch = 7 - w;
    const int qa2 = ch * 32 + lq;
    short8 qf2[4];
    const unsigned short* qp = &qkb[((bn << 8) + qa2) * 512 + (h << 5)];
    const unsigned short* tp = &tqtkb[((b << 8) + qa2) * 512 + (h << 5)];
    qf2[0] = *(const short8*)&qp[hi * 8];
    qf2[1] = *(const short8*)&qp[16 + hi * 8];
    qf2[2] = *(const short8*)&tp[hi * 8];
    qf2[3] = *(const short8*)&tp[16 + hi * 8];
    for (int g = 0; g <= ch - 4; ++g)
      attn_group(g << 5, qa2, hi, lq, qf2, KsB, VsB, bm0, bm1, bm2, bm3,
                 oacc2, lrun2);
  }

  __syncthreads();
  if (w < 4) {
    float* mo = (float*)(KsB + w * 4096);
#pragma unroll
    for (int r = 0; r < 16; ++r) mo[r * 64 + l] = oacc2[r];
    ((float*)(KsB + 16384))[w * 64 + l] = lrun2;
  }
  __syncthreads();
  if (w >= 4) {
    const float* mo = (const float*)(KsB + (7 - w) * 4096);
#pragma unroll
    for (int r = 0; r < 16; ++r) oacc[r] += mo[r * 64 + l];
    lrun += ((const float*)(KsB + 16384))[(7 - w) * 64 + l];
  }

  const float inv = 1.0f / fmaxf(lrun, 1e-6f);
  const int row = (bn << 8) + qa;
#pragma unroll
  for (int g2 = 0; g2 < 4; ++g2) {
    const unsigned long long h0 = f2bf(oacc[4 * g2 + 0] * inv);
    const unsigned long long h1 = f2bf(oacc[4 * g2 + 1] * inv);
    const unsigned long long h2 = f2bf(oacc[4 * g2 + 2] * inv);
    const unsigned long long h3 = f2bf(oacc[4 * g2 + 3] * inv);
    const unsigned long long pkt = h0 | (h1 << 16) | (h2 << 32) | (h3 << 48);
    *(unsigned long long*)&ao[row * 256 + (h << 5) + 8 * g2 + 4 * hi] = pkt;
  }
}

// ---------------------------------------------------------------------------
extern "C" void kernel_launch(void* const* d_in, const int* in_sizes, int n_in,
                              void* d_out, int out_size, void* d_ws, size_t ws_size,
                              hipStream_t stream) {
  const float* seq    = (const float*)d_in[0];
  const float* regs   = (const float*)d_in[1];
  const float* trs    = (const float*)d_in[2];
  const float* q_w    = (const float*)d_in[3];
  const float* q_b    = (const float*)d_in[4];
  const float* k_w    = (const float*)d_in[5];
  const float* k_b    = (const float*)d_in[6];
  const float* v_w    = (const float*)d_in[7];
  const float* v_b    = (const float*)d_in[8];
  const float* o_w    = (const float*)d_in[9];
  const float* o_b    = (const float*)d_in[10];
  const float* semb   = (const float*)d_in[11];
  const float* reg_w  = (const float*)d_in[12];
  const float* reg_b  = (const float*)d_in[13];
  const float* tr_w   = (const float*)d_in[14];
  const float* tr_b   = (const float*)d_in[15];
  const float* tq_w   = (const float*)d_in[16];
  const float* tq_b   = (const float*)d_in[17];
  const float* tk_w   = (const float*)d_in[18];
  const float* tk_b   = (const float*)d_in[19];
  const float* ff_w1  = (const float*)d_in[20];
  const float* ff_b1  = (const float*)d_in[21];
  const float* ff_w2  = (const float*)d_in[22];
  const float* ff_b2  = (const float*)d_in[23];
  const float* ln1_g  = (const float*)d_in[24];
  const float* ln1_b  = (const float*)d_in[25];
  const float* ln2_g  = (const float*)d_in[26];
  const float* ln2_b  = (const float*)d_in[27];
  const int*   valid  = (const int*)d_in[28];
  const int*   codes  = (const int*)d_in[29];

  float* f32ws = (float*)d_ws;
  float* ts    = f32ws;                 // 262144 f
  unsigned short* bws = (unsigned short*)(f32ws + 262144 + 8388608);
  unsigned short* flatb = bws;                    // 8388608  (x1b alias)
  unsigned short* fpb   = bws + 8388608;          // 8388608  (ao alias)
  unsigned short* qkb   = bws + 16777216;         // 16777216 (h1 alias)
  unsigned short* vb    = bws + 33554432;         // 8388608
  unsigned short* tqtkb = bws + 41943040;         // 524288
  unsigned short* wqk   = bws + 42467328;         // 131072
  unsigned short* wv    = bws + 42598400;         // 65536
  unsigned short* wo    = bws + 42663936;         // 65536
  unsigned short* wtqtk = bws + 42729472;         // 131072
  unsigned short* wff1  = bws + 42860544;         // 131072
  unsigned short* wff2  = bws + 42991616;         // 131072  (end 43122688)
  unsigned short* ao  = fpb;      // fpb dead after proj
  unsigned short* x1b = flatb;    // gemmln reads flatb (phase A) then writes
  unsigned short* h1  = qkb;      // qkb dead after attn
  float* outp = (float*)d_out;

  const float c2 = 0.25505402f;  // (1/sqrt(32)) * log2(e) -- folded into q/tq

  // 1. weights + time state + prep (one launch; prep recomputes ts inline)
  cvtts_kernel<<<7680, 256, 0, stream>>>(
      q_w, k_w, v_w, o_w, tq_w, tk_w, ff_w1, ff_w2,
      wqk, wv, wo, wtqtk, wff1, wff2,
      regs, trs, codes, semb, reg_w, reg_b, tr_w, tr_b, ts,
      seq, flatb, fpb);
  // 2. ALL projections in one launch (128x256 tiles): qk | v | tqtk
  proj_kernel<<<784, 256, 0, stream>>>(
      fpb, flatb, ts, wqk, wv, wtqtk,
      q_b, k_b, v_b, tq_b, tk_b, qkb, vb, tqtkb, c2);
  // 3. attention
  attn6_kernel<<<BN_ * NH_, 512, 0, stream>>>(qkb, vb, tqtkb, valid, ao);
  // 4. FUSED o-proj + flat residual + LN1 -> x1b (bf16)
  gemmln_kernel<256, false><<<M_ / 64, 256, 0, stream>>>(
      ao, wo, o_b, flatb, ln1_g, ln1_b, nullptr, x1b);
  // 5. FF1 (GELU, 128x256 tiles)
  mmb_kernel<256, 512><<<dim3(256, 2), 256, 0, stream>>>(x1b, wff1, ff_b1, h1);
  // 6. FUSED ff2 + x1 residual + LN2 + valid + scatter -> out
  gemmln_kernel<512, true><<<M_ / 64, 256, 0, stream>>>(
      h1, wff2, ff_b2, x1b, ln2_g, ln2_b, valid, outp);
}

// Round 18
// 158.501 us; speedup vs baseline: 1.1982x; 1.1982x over previous
//
#include <hip/hip_runtime.h>
#include <math.h>

// Shapes (fixed)
#define B_ 4
#define S_ 256
#define N_ 32
#define H_ 256
#define NH_ 8
#define HD_ 32
#define FF_ 512
#define BN_ 128
#define M_ 32768   // BN_*S_
#define BS_ 1024   // B_*S_

typedef __attribute__((ext_vector_type(8))) short short8;
typedef __attribute__((ext_vector_type(4))) short short4v;
typedef __attribute__((ext_vector_type(4))) float f32x4;
typedef __attribute__((ext_vector_type(16))) float f32x16;
typedef __attribute__((ext_vector_type(4))) int i32x4;

__device__ __forceinline__ unsigned short f2bf(float f) {
  unsigned u = __builtin_bit_cast(unsigned, f);
  u = (u + 0x7FFFu + ((u >> 16) & 1u)) >> 16;
  return (unsigned short)u;
}
__device__ __forceinline__ float bf2f(unsigned short h) {
  unsigned u = ((unsigned)h) << 16;
  return __builtin_bit_cast(float, u);
}

// Direct global->LDS DMA, 16B per lane (lands at wave-uniform base + lane*16).
__device__ __forceinline__ void gload16(const void* g, void* l) {
  __builtin_amdgcn_global_load_lds(
      (const __attribute__((address_space(1))) unsigned*)g,
      (__attribute__((address_space(3))) unsigned*)l, 16, 0, 0);
}

// ---------------------------------------------------------------------------
// cvtts + prep merged (one launch):
// blocks 0..2559:    W[K][N] fp32 -> Wt[N][K] bf16 (8 weight regions)
// blocks 2560..3583: ts[bs][h]
// blocks 3584..7679: prep rows: flatb = bf16(seq), fpb = bf16(seq + ts_inline)
// ---------------------------------------------------------------------------
__global__ __launch_bounds__(256)
void cvtts_kernel(const float* __restrict__ q_w, const float* __restrict__ k_w,
                  const float* __restrict__ v_w, const float* __restrict__ o_w,
                  const float* __restrict__ tq_w, const float* __restrict__ tk_w,
                  const float* __restrict__ ff1_w, const float* __restrict__ ff2_w,
                  unsigned short* __restrict__ wqk, unsigned short* __restrict__ wv,
                  unsigned short* __restrict__ wo, unsigned short* __restrict__ wtqtk,
                  unsigned short* __restrict__ wff1, unsigned short* __restrict__ wff2,
                  const float* __restrict__ reg, const float* __restrict__ tr,
                  const int* __restrict__ codes, const float* __restrict__ semb,
                  const float* __restrict__ reg_w, const float* __restrict__ reg_b,
                  const float* __restrict__ tr_w, const float* __restrict__ tr_b,
                  float* __restrict__ ts,
                  const float* __restrict__ seq,
                  unsigned short* __restrict__ flatb,
                  unsigned short* __restrict__ fpb) {
  const int bid = blockIdx.x, tid = threadIdx.x;
  if (bid >= 3584) {   // prep region
    const int row = (bid - 3584) * 8 + (tid >> 5);
    const int c0 = (tid & 31) * 8;
    const int bn = row >> 8, s = row & 255;
    const int b = bn >> 5, n = bn & 31;
    const int bs = (b << 8) + s;
    int c = codes[bs];
    c = c < 0 ? 0 : (c > 7 ? 7 : c);
    const float r = reg[bs], t = tr[bs];
    const float* sp = &seq[(((bs << 5)) + n) * 256 + c0];
    const float4 a0 = *(const float4*)sp, a1 = *(const float4*)(sp + 4);
    short8 fv, gv;
    float av[8] = {a0.x, a0.y, a0.z, a0.w, a1.x, a1.y, a1.z, a1.w};
#pragma unroll
    for (int j = 0; j < 8; ++j) {
      const int hcol = c0 + j;
      const float tsv = semb[c * H_ + hcol] + r * reg_w[hcol] + reg_b[hcol]
                        + t * tr_w[hcol] + tr_b[hcol];
      fv[j] = (short)f2bf(av[j]);
      gv[j] = (short)f2bf(av[j] + tsv);
    }
    *(short8*)&flatb[row * 256 + c0] = fv;
    *(short8*)&fpb[row * 256 + c0] = gv;
    return;
  }
  if (bid >= 2560) {   // time_state region
    const int bs = bid - 2560;
    int c = codes[bs];
    c = c < 0 ? 0 : (c > 7 ? 7 : c);
    const float r = reg[bs], t = tr[bs];
    ts[bs * H_ + tid] = semb[c * H_ + tid] + r * reg_w[tid] + reg_b[tid]
                        + t * tr_w[tid] + tr_b[tid];
    return;
  }
  const float* src; unsigned short* dst; int ns, K, base;
  if (bid < 256)       { src = q_w;   dst = wqk;           ns = 8; K = 256; base = 0; }
  else if (bid < 512)  { src = k_w;   dst = wqk + 65536;   ns = 8; K = 256; base = 256; }
  else if (bid < 768)  { src = v_w;   dst = wv;            ns = 8; K = 256; base = 512; }
  else if (bid < 1024) { src = o_w;   dst = wo;            ns = 8; K = 256; base = 768; }
  else if (bid < 1280) { src = tq_w;  dst = wtqtk;         ns = 8; K = 256; base = 1024; }
  else if (bid < 1536) { src = tk_w;  dst = wtqtk + 65536; ns = 8; K = 256; base = 1280; }
  else if (bid < 2048) { src = ff1_w; dst = wff1;          ns = 9; K = 256; base = 1536; }
  else                 { src = ff2_w; dst = wff2;          ns = 8; K = 512; base = 2048; }
  const int idx = (bid - base) * 256 + tid;
  const int k = idx >> ns, n = idx & ((1 << ns) - 1);
  dst[n * K + k] = f2bf(src[idx]);
}

// ---------------------------------------------------------------------------
// Combined projection kernel (one launch, three regions by blockIdx):
//  region 0 (blocks 0..1023):   qk   = (fpb @ wqk) +[q_b|k_b], q-half *c2
//  region 1 (blocks 1024..1535): v   = (flatb @ wv) + v_b
//  region 2 (blocks 1536..1567): tqtk= (ts @ wtqtk) +[tq_b|tk_b], tq *0.25c2
// 128x128 tile, BK=64. LDS XOR-swizzled (T2): staged via pre-swizzled global
// source granule (l&7)^(l>>3) with linear gload16 dest; reads XOR by
// ((lr&7)<<3). Region-2 manual stores apply the same XOR on the write addr.
// ---------------------------------------------------------------------------
__global__ __launch_bounds__(256)
void proj_kernel(const unsigned short* __restrict__ fpb,
                 const unsigned short* __restrict__ flatb,
                 const float* __restrict__ ts,
                 const unsigned short* __restrict__ wqk,
                 const unsigned short* __restrict__ wv,
                 const unsigned short* __restrict__ wtqtk,
                 const float* __restrict__ q_b, const float* __restrict__ k_b,
                 const float* __restrict__ v_b,
                 const float* __restrict__ tq_b, const float* __restrict__ tk_b,
                 unsigned short* __restrict__ qkb, unsigned short* __restrict__ vb,
                 unsigned short* __restrict__ tqtkb, float c2) {
  __shared__ unsigned short As[128 * 64];
  __shared__ unsigned short Bs[128 * 64];
  const int bid = blockIdx.x, tid = threadIdx.x;
  const int l = tid & 63, w = tid >> 6;
  const int wr = w >> 1, wc = w & 1;
  const int lr = l & 15, lg = l >> 4;
  const int sw = (lr & 7) << 3;        // read-side XOR (shorts)

  int region, m0, n0, NOUT;
  const unsigned short* Ab = nullptr;
  const float* Af = nullptr;
  const unsigned short* Wt;
  const float* b0; const float* b1;
  unsigned short* Cv; float scl;
  if (bid < 1024) {
    region = 0; m0 = (bid & 255) * 128; n0 = (bid >> 8) * 128; NOUT = 512;
    Ab = fpb; Wt = wqk; b0 = q_b; b1 = k_b; Cv = qkb; scl = c2;
  } else if (bid < 1536) {
    const int idx = bid - 1024;
    region = 1; m0 = (idx & 255) * 128; n0 = (idx >> 8) * 128; NOUT = 256;
    Ab = flatb; Wt = wv; b0 = v_b; b1 = v_b; Cv = vb; scl = 1.0f;
  } else {
    const int idx = bid - 1536;
    region = 2; m0 = (idx & 7) * 128; n0 = (idx >> 3) * 128; NOUT = 512;
    Af = ts; Wt = wtqtk; b0 = tq_b; b1 = tk_b; Cv = tqtkb; scl = 0.25f * c2;
  }

  f32x4 acc[4][4] = {};
  const int cg = (l & 7) ^ (l >> 3);   // pre-swizzled source granule
  const unsigned short* ga = (region != 2)
      ? Ab + (m0 + w * 32 + (l >> 3)) * 256 + cg * 8 : nullptr;
  const unsigned short* gb = Wt + (n0 + w * 32 + (l >> 3)) * 256 + cg * 8;

  for (int k0 = 0; k0 < 256; k0 += 64) {
    if (region != 2) {
#pragma unroll
      for (int i = 0; i < 4; ++i)
        gload16(ga + k0 + i * 8 * 256, &As[(w * 32 + i * 8) * 64]);
    } else {
#pragma unroll
      for (int i = 0; i < 8; ++i) {
        const int seg = i * 256 + tid;
        const int r = seg >> 4, c4 = (seg & 15) * 4;
        const float4 a4 = *(const float4*)&Af[(m0 + r) * 256 + k0 + c4];
        short4v sv;
        sv[0] = (short)f2bf(a4.x); sv[1] = (short)f2bf(a4.y);
        sv[2] = (short)f2bf(a4.z); sv[3] = (short)f2bf(a4.w);
        *(short4v*)&As[r * 64 + (c4 ^ ((r & 7) << 3))] = sv;
      }
    }
#pragma unroll
    for (int i = 0; i < 4; ++i)
      gload16(gb + k0 + i * 8 * 256, &Bs[(w * 32 + i * 8) * 64]);
    __syncthreads();
#pragma unroll
    for (int ks = 0; ks < 2; ++ks) {
      short8 af[4], bfr[4];
#pragma unroll
      for (int qt = 0; qt < 4; ++qt)
        af[qt] = *(const short8*)&As[(wr * 64 + qt * 16 + lr) * 64
                                     + ((ks * 32 + lg * 8) ^ sw)];
#pragma unroll
      for (int nt = 0; nt < 4; ++nt)
        bfr[nt] = *(const short8*)&Bs[(wc * 64 + nt * 16 + lr) * 64
                                      + ((ks * 32 + lg * 8) ^ sw)];
#pragma unroll
      for (int qt = 0; qt < 4; ++qt)
#pragma unroll
        for (int nt = 0; nt < 4; ++nt)
          acc[qt][nt] = __builtin_amdgcn_mfma_f32_16x16x32_bf16(
              af[qt], bfr[nt], acc[qt][nt], 0, 0, 0);
    }
    __syncthreads();
  }

#pragma unroll
  for (int qt = 0; qt < 4; ++qt) {
#pragma unroll
    for (int nt = 0; nt < 4; ++nt) {
      const int col = n0 + wc * 64 + nt * 16 + lr;
      const float bsv = (col < 256) ? b0[col] : b1[col - 256];
      const float sc = (col < 256) ? scl : 1.0f;
#pragma unroll
      for (int i = 0; i < 4; ++i) {
        const int row = m0 + wr * 64 + qt * 16 + (lg << 2) + i;
        Cv[row * NOUT + col] = f2bf((acc[qt][nt][i] + bsv) * sc);
      }
    }
  }
}

// ---------------------------------------------------------------------------
// bf16 MFMA GEMM (ff1 only): C = gelu(A @ W + bias), bf16 out.
// Same T2 swizzle as proj. 128x128 tile.
// ---------------------------------------------------------------------------
template<int K, int NOUT>
__global__ __launch_bounds__(256)
void mmb_kernel(const unsigned short* __restrict__ Ab,
                const unsigned short* __restrict__ Wt,
                const float* __restrict__ bias,
                unsigned short* __restrict__ Cv) {
  __shared__ unsigned short As[128 * 64];
  __shared__ unsigned short Bs[128 * 64];
  const int tid = threadIdx.x;
  const int m0 = blockIdx.x * 128, n0 = blockIdx.y * 128;
  const int l = tid & 63, w = tid >> 6;
  const int wr = w >> 1, wc = w & 1;
  const int lr = l & 15, lg = l >> 4;
  const int sw = (lr & 7) << 3;
  f32x4 acc[4][4] = {};

  const int cg = (l & 7) ^ (l >> 3);
  const unsigned short* ga = Ab + (m0 + w * 32 + (l >> 3)) * K + cg * 8;
  const unsigned short* gb = Wt + (n0 + w * 32 + (l >> 3)) * K + cg * 8;

  for (int k0 = 0; k0 < K; k0 += 64) {
#pragma unroll
    for (int i = 0; i < 4; ++i) {
      gload16(ga + k0 + i * 8 * K, &As[(w * 32 + i * 8) * 64]);
      gload16(gb + k0 + i * 8 * K, &Bs[(w * 32 + i * 8) * 64]);
    }
    __syncthreads();
#pragma unroll
    for (int ks = 0; ks < 2; ++ks) {
      short8 af[4], bfr[4];
#pragma unroll
      for (int qt = 0; qt < 4; ++qt)
        af[qt] = *(const short8*)&As[(wr * 64 + qt * 16 + lr) * 64
                                     + ((ks * 32 + lg * 8) ^ sw)];
#pragma unroll
      for (int nt = 0; nt < 4; ++nt)
        bfr[nt] = *(const short8*)&Bs[(wc * 64 + nt * 16 + lr) * 64
                                      + ((ks * 32 + lg * 8) ^ sw)];
#pragma unroll
      for (int qt = 0; qt < 4; ++qt)
#pragma unroll
        for (int nt = 0; nt < 4; ++nt)
          acc[qt][nt] = __builtin_amdgcn_mfma_f32_16x16x32_bf16(
              af[qt], bfr[nt], acc[qt][nt], 0, 0, 0);
    }
    __syncthreads();
  }

#pragma unroll
  for (int qt = 0; qt < 4; ++qt) {
#pragma unroll
    for (int nt = 0; nt < 4; ++nt) {
      const int col = n0 + wc * 64 + nt * 16 + lr;
      const float bsv = bias[col];
#pragma unroll
      for (int i = 0; i < 4; ++i) {
        const int row = m0 + wr * 64 + qt * 16 + (lg << 2) + i;
        float v = acc[qt][nt][i] + bsv;
        v = 0.5f * v * (1.0f + erff(v * 0.70710678118654752f));
        Cv[row * NOUT + col] = f2bf(v);
      }
    }
  }
}

// ---------------------------------------------------------------------------
// Fused GEMM (NOUT=256, full row per block) + residual + LayerNorm.
// FINAL=false: write bf16 [M][256] (LN1). FINAL=true: fp32 *valid scatter.
// ---------------------------------------------------------------------------
template<int K, bool FINAL>
__global__ __launch_bounds__(256, 2)
void gemmln_kernel(const unsigned short* __restrict__ Ab,   // [M][K] bf16
                   const unsigned short* __restrict__ Wt,   // [256][K] bf16
                   const float* __restrict__ bias,
                   const unsigned short* __restrict__ resb, // [M][256] bf16
                   const float* __restrict__ g, const float* __restrict__ bb,
                   const int* __restrict__ valid,
                   void* __restrict__ out) {
  __shared__ unsigned short As[64 * 64];    // 8 KB
  __shared__ unsigned short Bs[256 * 64];   // 32 KB
  __shared__ float Red[4][64][2];           // 2 KB
  const int tid = threadIdx.x;
  const int m0 = blockIdx.x * 64;
  const int l = tid & 63, w = tid >> 6;     // w = col quarter
  const int lr = l & 15, lg = l >> 4;
  f32x4 acc[4][4] = {};

  const unsigned short* ga = Ab + (m0 + w * 16 + (l >> 3)) * K + (l & 7) * 8;
  const unsigned short* gb = Wt + (w * 64 + (l >> 3)) * K + (l & 7) * 8;

  for (int k0 = 0; k0 < K; k0 += 64) {
#pragma unroll
    for (int i = 0; i < 2; ++i)
      gload16(ga + k0 + i * 8 * K, &As[(w * 16 + i * 8) * 64]);
#pragma unroll
    for (int i = 0; i < 8; ++i)
      gload16(gb + k0 + i * 8 * K, &Bs[(w * 64 + i * 8) * 64]);
    __syncthreads();
#pragma unroll
    for (int ks = 0; ks < 2; ++ks) {
      short8 af[4], bfr[4];
#pragma unroll
      for (int qt = 0; qt < 4; ++qt)
        af[qt] = *(const short8*)&As[(qt * 16 + lr) * 64 + ks * 32 + lg * 8];
#pragma unroll
      for (int nt = 0; nt < 4; ++nt)
        bfr[nt] = *(const short8*)&Bs[(w * 64 + nt * 16 + lr) * 64 + ks * 32 + lg * 8];
#pragma unroll
      for (int qt = 0; qt < 4; ++qt)
#pragma unroll
        for (int nt = 0; nt < 4; ++nt)
          acc[qt][nt] = __builtin_amdgcn_mfma_f32_16x16x32_bf16(
              af[qt], bfr[nt], acc[qt][nt], 0, 0, 0);
    }
    __syncthreads();
  }

  // Phase A: x = acc + bias + residual; per-row partial sums -> Red[w]
#pragma unroll
  for (int qt = 0; qt < 4; ++qt) {
#pragma unroll
    for (int i = 0; i < 4; ++i) {
      const int rl = qt * 16 + (lg << 2) + i;
      const int row = m0 + rl;
      float s1 = 0.0f, s2 = 0.0f;
#pragma unroll
      for (int nt = 0; nt < 4; ++nt) {
        const int col = w * 64 + nt * 16 + lr;
        float v = acc[qt][nt][i] + bias[col] + bf2f(resb[row * 256 + col]);
        acc[qt][nt][i] = v;
        s1 += v; s2 += v * v;
      }
      s1 += __shfl_xor(s1, 1); s2 += __shfl_xor(s2, 1);
      s1 += __shfl_xor(s1, 2); s2 += __shfl_xor(s2, 2);
      s1 += __shfl_xor(s1, 4); s2 += __shfl_xor(s2, 4);
      s1 += __shfl_xor(s1, 8); s2 += __shfl_xor(s2, 8);
      if (lr == 0) { Red[w][rl][0] = s1; Red[w][rl][1] = s2; }
    }
  }
  __syncthreads();

  // Phase B: combine 4 quarters, normalize, write own cols
#pragma unroll
  for (int qt = 0; qt < 4; ++qt) {
#pragma unroll
    for (int i = 0; i < 4; ++i) {
      const int rl = qt * 16 + (lg << 2) + i;
      const int row = m0 + rl;
      const float s1 = (Red[0][rl][0] + Red[1][rl][0])
                     + (Red[2][rl][0] + Red[3][rl][0]);
      const float s2 = (Red[0][rl][1] + Red[1][rl][1])
                     + (Red[2][rl][1] + Red[3][rl][1]);
      const float mean = s1 * (1.0f / 256.0f);
      const float var = s2 * (1.0f / 256.0f) - mean * mean;
      const float rstd = rsqrtf(var + 1e-5f);
      if (FINAL) {
        const int bn = row >> 8, s = row & 255;
        const int b = bn >> 5, n = bn & 31;
        const float vm = (valid[((b << 8) + s) * 32 + n] != 0) ? 1.0f : 0.0f;
        float* op = (float*)out + ((((b << 8) + s) << 5) + n) * 256;
#pragma unroll
        for (int nt = 0; nt < 4; ++nt) {
          const int col = w * 64 + nt * 16 + lr;
          op[col] = ((acc[qt][nt][i] - mean) * rstd * g[col] + bb[col]) * vm;
        }
      } else {
        unsigned short* op = (unsigned short*)out + row * 256;
#pragma unroll
        for (int nt = 0; nt < 4; ++nt) {
          const int col = w * 64 + nt * 16 + lr;
          op[col] = f2bf((acc[qt][nt][i] - mean) * rstd * g[col] + bb[col]);
        }
      }
    }
  }
}

// ---------------------------------------------------------------------------
// One key-group step of the swapped-operand flash attention.
// ---------------------------------------------------------------------------
__device__ __forceinline__ void attn_group(
    const int kbase, const int qa, const int hi, const int lq,
    const short8* __restrict__ qf,
    const char* __restrict__ KsB, const char* __restrict__ VsB,
    const unsigned long long bm0, const unsigned long long bm1,
    const unsigned long long bm2, const unsigned long long bm3,
    f32x16& oacc, float& lrun) {
  f32x16 s = {};
#pragma unroll
  for (int df = 0; df < 4; ++df) {
    const int key = kbase + lq;
    const short8 akf = *(const short8*)(
        KsB + key * 128 + ((df * 32 + hi * 16) ^ ((key & 7) << 4)));
    s = __builtin_amdgcn_mfma_f32_32x32x16_bf16(akf, qf[df], s, 0, 0, 0);
  }
  const unsigned long long bmc = (kbase < 64) ? bm0 : (kbase < 128) ? bm1
                               : (kbase < 192) ? bm2 : bm3;
  const unsigned wnd = (kbase & 32) ? (unsigned)(bmc >> 32) : (unsigned)bmc;
  float p[16];
#pragma unroll
  for (int r = 0; r < 16; ++r) {
    const int crow = (r & 3) + 8 * (r >> 2) + 4 * hi;
    const int key = kbase + crow;
    const bool ok = (key <= qa) && (((wnd >> crow) & 1u) != 0u);
    p[r] = ok ? __builtin_amdgcn_exp2f(s[r]) : 0.0f;
  }
  float rs = ((p[0] + p[1]) + (p[2] + p[3])) + ((p[4] + p[5]) + (p[6] + p[7]))
           + ((p[8] + p[9]) + (p[10] + p[11])) + ((p[12] + p[13]) + (p[14] + p[15]));
  rs += __shfl_xor(rs, 32);
  lrun += rs;
  unsigned wds[8];
#pragma unroll
  for (int i2 = 0; i2 < 8; ++i2)
    wds[i2] = (unsigned)f2bf(p[2 * i2]) | ((unsigned)f2bf(p[2 * i2 + 1]) << 16);
  unsigned xw[8];
#pragma unroll
  for (int i2 = 0; i2 < 8; ++i2)
    xw[i2] = (unsigned)__shfl_xor((int)wds[i2], 32);
  i32x4 f0, f1;
  f0[0] = (int)(hi ? xw[2] : wds[0]);
  f0[1] = (int)(hi ? xw[3] : wds[1]);
  f0[2] = (int)(hi ? wds[2] : xw[0]);
  f0[3] = (int)(hi ? wds[3] : xw[1]);
  f1[0] = (int)(hi ? xw[6] : wds[4]);
  f1[1] = (int)(hi ? xw[7] : wds[5]);
  f1[2] = (int)(hi ? wds[6] : xw[4]);
  f1[3] = (int)(hi ? wds[7] : xw[5]);
  const short8 pf0 = __builtin_bit_cast(short8, f0);
  const short8 pf1 = __builtin_bit_cast(short8, f1);
  {
    const short8 avf = *(const short8*)(
        VsB + lq * 512 + (((kbase + hi * 8) * 2) ^ ((lq & 7) << 4)));
    oacc = __builtin_amdgcn_mfma_f32_32x32x16_bf16(avf, pf0, oacc, 0, 0, 0);
  }
  {
    const short8 avf = *(const short8*)(
        VsB + lq * 512 + (((kbase + 16 + hi * 8) * 2) ^ ((lq & 7) << 4)));
    oacc = __builtin_amdgcn_mfma_f32_32x32x16_bf16(avf, pf1, oacc, 0, 0, 0);
  }
}

// ---------------------------------------------------------------------------
// Attention (unchanged): 8 waves, 48KB LDS, balanced helper waves;
// XCD swizzle; async K'-staging; direct stores.
// ---------------------------------------------------------------------------
__global__ __launch_bounds__(512, 4)
void attn6_kernel(const unsigned short* __restrict__ qkb,   // [M][512] q|k
                  const unsigned short* __restrict__ vb,    // [M][256]
                  const unsigned short* __restrict__ tqtkb, // [BS][512] tq|tk
                  const int* __restrict__ valid,
                  unsigned short* __restrict__ ao) {
  __shared__ __align__(16) char KsB[256 * 128];   // K' [key][d64]; merge alias
  __shared__ __align__(16) char VsB[32 * 512];    // V^T [dv][key], swizzled

  const int bn = blockIdx.x & 127;      // XCD swizzle
  const int h = blockIdx.x >> 7;
  const int b = bn >> 5, n = bn & 31;
  const int tid = threadIdx.x, l = tid & 63, w = tid >> 6;  // w = query chunk
  const int lq = l & 31, hi = l >> 5;
  const int qa = w * 32 + lq;          // this lane's query row

  const unsigned long long bm0 = __ballot(valid[((b << 8) + 0   + l) * 32 + n] != 0);
  const unsigned long long bm1 = __ballot(valid[((b << 8) + 64  + l) * 32 + n] != 0);
  const unsigned long long bm2 = __ballot(valid[((b << 8) + 128 + l) * 32 + n] != 0);
  const unsigned long long bm3 = __ballot(valid[((b << 8) + 192 + l) * 32 + n] != 0);

  short8 qf[4];
  {
    const unsigned short* qp = &qkb[((bn << 8) + qa) * 512 + (h << 5)];
    const unsigned short* tp = &tqtkb[((b << 8) + qa) * 512 + (h << 5)];
    qf[0] = *(const short8*)&qp[hi * 8];
    qf[1] = *(const short8*)&qp[16 + hi * 8];
    qf[2] = *(const short8*)&tp[hi * 8];
    qf[3] = *(const short8*)&tp[16 + hi * 8];
  }

  // stage K' via async DMA with pre-swizzled source
  {
    const int cp = (l & 7) ^ (l >> 3);
    const unsigned short* base0 = (cp < 4)
        ? &qkb[((bn << 8) + (l >> 3)) * 512 + 256 + (h << 5) + cp * 8]
        : &tqtkb[((b << 8) + (l >> 3)) * 512 + 256 + (h << 5) + (cp - 4) * 8];
#pragma unroll
    for (int i = 0; i < 4; ++i) {
      const int kb0 = i * 64 + w * 8;   // wave-uniform base key
      gload16(base0 + kb0 * 512, KsB + kb0 * 128);
    }
  }
  // stage V^T (manual transpose), swizzled
#pragma unroll
  for (int i = 0; i < 2; ++i) {
    const int e = i * 512 + tid;
    const int key = e >> 2, c = e & 3;
    const short8 v = *(const short8*)&vb[((bn << 8) + key) * 256 + (h << 5) + c * 8];
#pragma unroll
    for (int j = 0; j < 8; ++j) {
      const int dv = c * 8 + j;
      *(unsigned short*)(VsB + dv * 512 + ((key * 2) ^ ((dv & 7) << 4))) =
          (unsigned short)v[j];
    }
  }
  __syncthreads();

  f32x16 oacc = {}, oacc2 = {};
  float lrun = 0.0f, lrun2 = 0.0f;

  const int gstart = (w >= 4) ? (w - 3) : 0;
  for (int g = gstart; g <= w; ++g)
    attn_group(g << 5, qa, hi, lq, qf, KsB, VsB, bm0, bm1, bm2, bm3, oacc, lrun);

  if (w < 4) {
    const int ch = 7 - w;
    const int qa2 = ch * 32 + lq;
    short8 qf2[4];
    const unsigned short* qp = &qkb[((bn << 8) + qa2) * 512 + (h << 5)];
    const unsigned short* tp = &tqtkb[((b << 8) + qa2) * 512 + (h << 5)];
    qf2[0] = *(const short8*)&qp[hi * 8];
    qf2[1] = *(const short8*)&qp[16 + hi * 8];
    qf2[2] = *(const short8*)&tp[hi * 8];
    qf2[3] = *(const short8*)&tp[16 + hi * 8];
    for (int g = 0; g <= ch - 4; ++g)
      attn_group(g << 5, qa2, hi, lq, qf2, KsB, VsB, bm0, bm1, bm2, bm3,
                 oacc2, lrun2);
  }

  __syncthreads();
  if (w < 4) {
    float* mo = (float*)(KsB + w * 4096);
#pragma unroll
    for (int r = 0; r < 16; ++r) mo[r * 64 + l] = oacc2[r];
    ((float*)(KsB + 16384))[w * 64 + l] = lrun2;
  }
  __syncthreads();
  if (w >= 4) {
    const float* mo = (const float*)(KsB + (7 - w) * 4096);
#pragma unroll
    for (int r = 0; r < 16; ++r) oacc[r] += mo[r * 64 + l];
    lrun += ((const float*)(KsB + 16384))[(7 - w) * 64 + l];
  }

  const float inv = 1.0f / fmaxf(lrun, 1e-6f);
  const int row = (bn << 8) + qa;
#pragma unroll
  for (int g2 = 0; g2 < 4; ++g2) {
    const unsigned long long h0 = f2bf(oacc[4 * g2 + 0] * inv);
    const unsigned long long h1 = f2bf(oacc[4 * g2 + 1] * inv);
    const unsigned long long h2 = f2bf(oacc[4 * g2 + 2] * inv);
    const unsigned long long h3 = f2bf(oacc[4 * g2 + 3] * inv);
    const unsigned long long pkt = h0 | (h1 << 16) | (h2 << 32) | (h3 << 48);
    *(unsigned long long*)&ao[row * 256 + (h << 5) + 8 * g2 + 4 * hi] = pkt;
  }
}

// ---------------------------------------------------------------------------
extern "C" void kernel_launch(void* const* d_in, const int* in_sizes, int n_in,
                              void* d_out, int out_size, void* d_ws, size_t ws_size,
                              hipStream_t stream) {
  const float* seq    = (const float*)d_in[0];
  const float* regs   = (const float*)d_in[1];
  const float* trs    = (const float*)d_in[2];
  const float* q_w    = (const float*)d_in[3];
  const float* q_b    = (const float*)d_in[4];
  const float* k_w    = (const float*)d_in[5];
  const float* k_b    = (const float*)d_in[6];
  const float* v_w    = (const float*)d_in[7];
  const float* v_b    = (const float*)d_in[8];
  const float* o_w    = (const float*)d_in[9];
  const float* o_b    = (const float*)d_in[10];
  const float* semb   = (const float*)d_in[11];
  const float* reg_w  = (const float*)d_in[12];
  const float* reg_b  = (const float*)d_in[13];
  const float* tr_w   = (const float*)d_in[14];
  const float* tr_b   = (const float*)d_in[15];
  const float* tq_w   = (const float*)d_in[16];
  const float* tq_b   = (const float*)d_in[17];
  const float* tk_w   = (const float*)d_in[18];
  const float* tk_b   = (const float*)d_in[19];
  const float* ff_w1  = (const float*)d_in[20];
  const float* ff_b1  = (const float*)d_in[21];
  const float* ff_w2  = (const float*)d_in[22];
  const float* ff_b2  = (const float*)d_in[23];
  const float* ln1_g  = (const float*)d_in[24];
  const float* ln1_b  = (const float*)d_in[25];
  const float* ln2_g  = (const float*)d_in[26];
  const float* ln2_b  = (const float*)d_in[27];
  const int*   valid  = (const int*)d_in[28];
  const int*   codes  = (const int*)d_in[29];

  float* f32ws = (float*)d_ws;
  float* ts    = f32ws;                 // 262144 f
  unsigned short* bws = (unsigned short*)(f32ws + 262144 + 8388608);
  unsigned short* flatb = bws;                    // 8388608  (x1b alias)
  unsigned short* fpb   = bws + 8388608;          // 8388608  (ao alias)
  unsigned short* qkb   = bws + 16777216;         // 16777216 (h1 alias)
  unsigned short* vb    = bws + 33554432;         // 8388608
  unsigned short* tqtkb = bws + 41943040;         // 524288
  unsigned short* wqk   = bws + 42467328;         // 131072
  unsigned short* wv    = bws + 42598400;         // 65536
  unsigned short* wo    = bws + 42663936;         // 65536
  unsigned short* wtqtk = bws + 42729472;         // 131072
  unsigned short* wff1  = bws + 42860544;         // 131072
  unsigned short* wff2  = bws + 42991616;         // 131072  (end 43122688)
  unsigned short* ao  = fpb;      // fpb dead after proj
  unsigned short* x1b = flatb;    // gemmln reads flatb (phase A) then writes
  unsigned short* h1  = qkb;      // qkb dead after attn
  float* outp = (float*)d_out;

  const float c2 = 0.25505402f;  // (1/sqrt(32)) * log2(e) -- folded into q/tq

  // 1. weights + time state + prep (one launch; prep recomputes ts inline)
  cvtts_kernel<<<7680, 256, 0, stream>>>(
      q_w, k_w, v_w, o_w, tq_w, tk_w, ff_w1, ff_w2,
      wqk, wv, wo, wtqtk, wff1, wff2,
      regs, trs, codes, semb, reg_w, reg_b, tr_w, tr_b, ts,
      seq, flatb, fpb);
  // 2. ALL projections in one launch: qk | v | tqtk  (T2-swizzled LDS)
  proj_kernel<<<1568, 256, 0, stream>>>(
      fpb, flatb, ts, wqk, wv, wtqtk,
      q_b, k_b, v_b, tq_b, tk_b, qkb, vb, tqtkb, c2);
  // 3. attention
  attn6_kernel<<<BN_ * NH_, 512, 0, stream>>>(qkb, vb, tqtkb, valid, ao);
  // 4. FUSED o-proj + flat residual + LN1 -> x1b (bf16)
  gemmln_kernel<256, false><<<M_ / 64, 256, 0, stream>>>(
      ao, wo, o_b, flatb, ln1_g, ln1_b, nullptr, x1b);
  // 5. FF1 (GELU, T2-swizzled LDS)
  mmb_kernel<256, 512><<<dim3(256, 4), 256, 0, stream>>>(x1b, wff1, ff_b1, h1);
  // 6. FUSED ff2 + x1 residual + LN2 + valid + scatter -> out
  gemmln_kernel<512, true><<<M_ / 64, 256, 0, stream>>>(
      h1, wff2, ff_b2, x1b, ln2_g, ln2_b, valid, outp);
}